// Round 4
// baseline (210.903 us; speedup 1.0000x reference)
//
#include <hip/hip_runtime.h>
#include <math.h>

#define B_ 32
#define C_ 3
#define H_ 256
#define W_ 256
#define HW_ 65536
#define CHW_ 196608
#define TOT_ 6291456

// ---- ws layout (bytes) ----
#define VIEWS_OFF_B 0ull
#define HIST_OFF_B  (4ull * TOT_ * 4ull)            // 4 views of f32
#define STATE_OFF_B (HIST_OFF_B + 32ull*2048*4)     // 32 x {prefix, krem}
#define SCALE_OFF_B (STATE_OFF_B + 32ull*8)
#define PMAD_OFF_B  (SCALE_OFF_B + 32ull*4)
#define PDEV_OFF_B  (PMAD_OFF_B + 1536ull*4)
#define MEAN_OFF_B  (PDEV_OFF_B + 1536ull*4)

// ---- k_views geometry: full-width bands ----
#define RC_ 32       // center rows per block
#define WR_ 40       // window rows = RC_ + 8
#define RB_ 10       // rows per wave (4 waves)
#define NBAND_ 8     // 256 / RC_

__device__ __forceinline__ float g_of(float d, float delta) {
    return d * __builtin_amdgcn_rcpf(delta + fabsf(d));
}

__device__ __forceinline__ void cswap(float& a, float& b) {
    float lo = fminf(a, b), hi = fmaxf(a, b); a = lo; b = hi;
}
__device__ __forceinline__ float median5(float a0, float a1, float a2, float a3, float a4) {
    cswap(a0,a1); cswap(a3,a4); cswap(a2,a4); cswap(a2,a3); cswap(a0,a3);
    cswap(a0,a2); cswap(a1,a4); cswap(a1,a3); cswap(a1,a2);
    return a2;
}

// ---------------- K1: radix-select median of |x| per sample ----------------
__global__ void k_init(unsigned* state) {
    int t = threadIdx.x;
    if (t < 32) { state[2*t] = 0u; state[2*t+1] = 98303u; }  // (196608-1)//2
}

__global__ __launch_bounds__(256) void k_hist(const float* __restrict__ x,
                                              unsigned* __restrict__ ghist,
                                              const unsigned* __restrict__ state,
                                              unsigned matchmask, int shift) {
    __shared__ unsigned h[2048];
    int t = threadIdx.x, chunk = blockIdx.x, s = blockIdx.y;
    #pragma unroll
    for (int i = 0; i < 8; i++) h[t + 256*i] = 0u;
    __syncthreads();
    unsigned prefix = state[2*s];
    size_t base = (size_t)s*CHW_ + (size_t)chunk*4096;
    #pragma unroll
    for (int i = 0; i < 16; i++) {
        float v = x[base + i*256 + t];
        unsigned u = __float_as_uint(fabsf(v));
        if ((u & matchmask) == prefix) atomicAdd(&h[(u >> shift) & 2047u], 1u);
    }
    __syncthreads();
    #pragma unroll
    for (int i = 0; i < 8; i++) {
        unsigned c = h[t + 256*i];
        if (c) atomicAdd(&ghist[s*2048 + t + 256*i], c);
    }
}

__global__ __launch_bounds__(256) void k_select(unsigned* __restrict__ ghist,
                                                unsigned* __restrict__ state,
                                                float* __restrict__ scale,
                                                int shift, int final_pass) {
    __shared__ unsigned sc[256];
    int t = threadIdx.x, s = blockIdx.x;
    unsigned krem = state[2*s+1];
    unsigned v[8]; unsigned ts = 0;
    #pragma unroll
    for (int i = 0; i < 8; i++) { v[i] = ghist[s*2048 + t*8 + i]; ts += v[i]; }
    sc[t] = ts; __syncthreads();
    for (int off = 1; off < 256; off <<= 1) {
        unsigned a = sc[t];
        unsigned b = (t >= off) ? sc[t-off] : 0u;
        __syncthreads();
        sc[t] = a + b;
        __syncthreads();
    }
    unsigned incl = sc[t], base = incl - ts;
    if (ts > 0 && base <= krem && krem < incl) {
        unsigned c = base; int dig = -1; unsigned nk = 0;
        #pragma unroll
        for (int i = 0; i < 8; i++) {
            if (dig < 0) {
                if (krem < c + v[i]) { dig = t*8 + i; nk = krem - c; }
                else c += v[i];
            }
        }
        unsigned prefix = state[2*s] | ((unsigned)dig << shift);
        state[2*s] = prefix;
        state[2*s+1] = nk;
        if (final_pass) scale[s] = __uint_as_float(prefix) + 1e-8f;
    }
    #pragma unroll
    for (int i = 0; i < 8; i++) ghist[s*2048 + t*8 + i] = 0u;
}

// ---------------- K2: Huber-TV, register-resident column strips ----------------
// Full-width (256-col) tiles: no horizontal halo. Each of 4 waves owns a
// 10-row band; each lane owns 4 contiguous columns of that band in registers.
// dy gradients are in-register (rolling gprev); dx via __shfl. Band boundaries
// exchange 2 rows through LDS per iteration. Out-of-window ghosts use
// replicate (g=0): infection moves 1 row/iter, center rows are >=4 rows away.
// Image top/bottom handled by clamp-loaded replicas + per-iter register copies
// (exactly reproduces the reference's masked-zero boundary gradients).
__global__ __launch_bounds__(256, 4) void k_views(const float* __restrict__ x,
        float* __restrict__ views, const float* __restrict__ scale,
        float l0, float l1, float l2, float l3,
        float e0, float e1, float e2, float e3) {
    __shared__ float exch[4][2][256];
    const int t = threadIdx.x;
    const int lane = t & 63, wv = t >> 6;
    const int band = blockIdx.x, bc = blockIdx.y, view = blockIdx.z;
    const int b = bc / 3;
    const float lam = (view == 0) ? l0 : (view == 1) ? l1 : (view == 2) ? l2 : l3;
    const float del = (view == 0) ? e0 : (view == 1) ? e1 : (view == 2) ? e2 : e3;
    const int i0 = band * RC_;
    const float sc = scale[b];
    const float inv_sc = 1.0f / sc;
    const float* img = x + (size_t)bc * HW_;
    const int wr0 = wv * RB_;
    const int col = lane << 2;

    float4 s[RB_], xn[RB_];
    #pragma unroll
    for (int r = 0; r < RB_; r++) {
        int gi = i0 - 4 + wr0 + r;
        gi = gi < 0 ? 0 : (gi > 255 ? 255 : gi);
        float4 v = *(const float4*)(img + gi * W_ + col);
        v.x *= inv_sc; v.y *= inv_sc; v.z *= inv_sc; v.w *= inv_sc;
        s[r] = v; xn[r] = v;
    }
    float4 gt, gb;
    {
        int gi = i0 - 5 + wr0; gi = gi < 0 ? 0 : (gi > 255 ? 255 : gi);
        gt = *(const float4*)(img + gi * W_ + col);
        gt.x *= inv_sc; gt.y *= inv_sc; gt.z *= inv_sc; gt.w *= inv_sc;
    }
    {
        int gi = i0 - 4 + wr0 + RB_; gi = gi < 0 ? 0 : (gi > 255 ? 255 : gi);
        gb = *(const float4*)(img + gi * W_ + col);
        gb.x *= inv_sc; gb.y *= inv_sc; gb.z *= inv_sc; gb.w *= inv_sc;
    }

    const bool topblk = (band == 0), botblk = (band == NBAND_ - 1);
    const bool is0 = (lane == 0), is63 = (lane == 63);
    const int lnext = is63 ? 63 : lane + 1;
    const int lprev = is0 ? 0 : lane - 1;

    #pragma unroll 1
    for (int it = 0; it < 3; it++) {
        float4 gprev;
        gprev.x = g_of(s[0].x - gt.x, del);
        gprev.y = g_of(s[0].y - gt.y, del);
        gprev.z = g_of(s[0].z - gt.z, del);
        gprev.w = g_of(s[0].w - gt.w, del);
        #pragma unroll
        for (int r = 0; r < RB_; r++) {
            float4 a = s[r];
            float4 vn = gb;
            if (r < RB_ - 1) vn = s[r + 1];
            float vn3 = __shfl(a.x, lnext);
            float g0 = g_of(a.y - a.x, del);
            float g1 = g_of(a.z - a.y, del);
            float g2 = g_of(a.w - a.z, del);
            float g3 = g_of(vn3 - a.w, del);
            g3 = is63 ? 0.f : g3;
            float gxl = __shfl(g3, lprev);
            gxl = is0 ? 0.f : gxl;
            float4 gy;
            gy.x = g_of(vn.x - a.x, del);
            gy.y = g_of(vn.y - a.y, del);
            gy.z = g_of(vn.z - a.z, del);
            gy.w = g_of(vn.w - a.w, del);
            float dvx = (g0 - gxl) + (gy.x - gprev.x);
            float dvy = (g1 - g0)  + (gy.y - gprev.y);
            float dvz = (g2 - g1)  + (gy.z - gprev.z);
            float dvw = (g3 - g2)  + (gy.w - gprev.w);
            a.x = fmaf(-0.2f, fmaf(-lam, dvx, a.x - xn[r].x), a.x);
            a.y = fmaf(-0.2f, fmaf(-lam, dvy, a.y - xn[r].y), a.y);
            a.z = fmaf(-0.2f, fmaf(-lam, dvz, a.z - xn[r].z), a.z);
            a.w = fmaf(-0.2f, fmaf(-lam, dvw, a.w - xn[r].w), a.w);
            s[r] = a;
            gprev = gy;
        }
        if (it < 2) {
            __syncthreads();
            *(float4*)&exch[wv][0][col] = s[0];
            *(float4*)&exch[wv][1][col] = s[RB_ - 1];
            __syncthreads();
            gt = wv ? *(const float4*)&exch[wv - 1][1][col] : s[0];
            gb = (wv < 3) ? *(const float4*)&exch[wv + 1][0][col] : s[RB_ - 1];
            if (topblk && wv == 0) { s[0] = s[4]; s[1] = s[4]; s[2] = s[4]; s[3] = s[4]; gt = s[4]; }
            if (botblk && wv == 3) { s[6] = s[5]; s[7] = s[5]; s[8] = s[5]; s[9] = s[5]; gb = s[5]; }
        }
    }

    // store center rows (window rows 4 .. 4+RC_-1)
    float* vout = views + (size_t)view * TOT_ + (size_t)bc * HW_;
    #pragma unroll
    for (int r = 0; r < RB_; r++) {
        int wr = wr0 + r;
        if (wr >= 4 && wr < 4 + RC_) {
            int gi = i0 + wr - 4;
            float4 o = s[r];
            o.x *= sc; o.y *= sc; o.z *= sc; o.w *= sc;
            *(float4*)(vout + gi * W_ + col) = o;
        }
    }
}

// ---------------- K3: per-pixel med/dev/mad -> deterministic partials ----------------
__global__ __launch_bounds__(256) void k_stats(const float* __restrict__ x,
                                               const float* __restrict__ views,
                                               float* __restrict__ pmad,
                                               float* __restrict__ pdev) {
    int t = threadIdx.x, chunk = blockIdx.x, b = blockIdx.y;
    size_t base = (size_t)b*CHW_ + (size_t)chunk*4096;
    float am = 0.f, ad = 0.f;
    for (int i = 0; i < 16; i++) {
        size_t idx = base + i*256 + t;
        float s0 = x[idx];
        float s1 = views[idx];
        float s2 = views[(size_t)TOT_ + idx];
        float s3 = views[2ull*TOT_ + idx];
        float s4 = views[3ull*TOT_ + idx];
        float med = median5(s0, s1, s2, s3, s4);
        float d0 = fabsf(s0-med), d1 = fabsf(s1-med), d2 = fabsf(s2-med),
              d3 = fabsf(s3-med), d4 = fabsf(s4-med);
        float mad = median5(d0, d1, d2, d3, d4);
        am += mad;
        ad += d0 + d1 + d2 + d3 + d4;
    }
    __shared__ float r[256];
    r[t] = am; __syncthreads();
    for (int off = 128; off > 0; off >>= 1) { if (t < off) r[t] += r[t+off]; __syncthreads(); }
    if (t == 0) pmad[b*48 + chunk] = r[0];
    __syncthreads();
    r[t] = ad; __syncthreads();
    for (int off = 128; off > 0; off >>= 1) { if (t < off) r[t] += r[t+off]; __syncthreads(); }
    if (t == 0) pdev[b*48 + chunk] = r[0];
}

// ---------------- K4: finalize scalars (mad mean, beta) ----------------
__global__ __launch_bounds__(256) void k_final(const float* __restrict__ pmad,
                                               const float* __restrict__ pdev,
                                               float* __restrict__ meanp,
                                               float* __restrict__ out_beta) {
    __shared__ float r[256];
    int t = threadIdx.x;
    float s = 0.f;
    for (int j = t; j < 1536; j += 256) s += pmad[j];
    r[t] = s; __syncthreads();
    for (int off = 128; off > 0; off >>= 1) { if (t < off) r[t] += r[t+off]; __syncthreads(); }
    if (t == 0) meanp[0] = r[0] / (float)TOT_;
    if (t < 32) {
        float sd = 0.f;
        for (int j = 0; j < 48; j++) sd += pdev[t*48 + j];
        float D = sd / (5.0f * (float)CHW_);
        float z = (D - 0.02f) / 0.01f;
        out_beta[t] = 1.0f / (1.0f + __expf(-z));
    }
}

// ---------------- K5: fusion ----------------
__global__ __launch_bounds__(256) void k_fuse(const float* __restrict__ x,
                                              const float* __restrict__ views,
                                              const float* __restrict__ meanp,
                                              float* __restrict__ out) {
    int t = threadIdx.x;
    size_t base = (size_t)blockIdx.x * 4096;
    float floorv = 0.1f * meanp[0];
    for (int i = 0; i < 16; i++) {
        size_t idx = base + i*256 + t;
        float s0 = x[idx];
        float s1 = views[idx];
        float s2 = views[(size_t)TOT_ + idx];
        float s3 = views[2ull*TOT_ + idx];
        float s4 = views[3ull*TOT_ + idx];
        float med = median5(s0, s1, s2, s3, s4);
        float d0 = fabsf(s0-med), d1 = fabsf(s1-med), d2 = fabsf(s2-med),
              d3 = fabsf(s3-med), d4 = fabsf(s4-med);
        float mad = median5(d0, d1, d2, d3, d4);
        float madf = fmaxf(mad, floorv);
        float inv = 1.0f / (2.0f * madf);
        float w0 = __expf(-d0*inv), w1 = __expf(-d1*inv), w2 = __expf(-d2*inv),
              w3 = __expf(-d3*inv), w4 = __expf(-d4*inv);
        float num = w0*s0 + w1*s1 + w2*s2 + w3*s3 + w4*s4;
        float den = w0 + w1 + w2 + w3 + w4 + 1e-8f;
        out[idx] = num / den;
    }
}

extern "C" void kernel_launch(void* const* d_in, const int* in_sizes, int n_in,
                              void* d_out, int out_size, void* d_ws, size_t ws_size,
                              hipStream_t stream) {
    const float* x = (const float*)d_in[0];
    float* out = (float*)d_out;
    char* ws = (char*)d_ws;
    float*    views = (float*)(ws + VIEWS_OFF_B);
    unsigned* ghist = (unsigned*)(ws + HIST_OFF_B);
    unsigned* state = (unsigned*)(ws + STATE_OFF_B);
    float*    scale = (float*)(ws + SCALE_OFF_B);
    float*    pmad  = (float*)(ws + PMAD_OFF_B);
    float*    pdev  = (float*)(ws + PDEV_OFF_B);
    float*    meanp = (float*)(ws + MEAN_OFF_B);

    // param sets: replicate np.random.RandomState(0).uniform(-.1,.1) draws
    const double s4[4] = {0.5488135039273248, 0.7151893663724195,
                          0.6027633760716439, 0.5448831829968969};
    float lam[4], del[4];
    for (int i = 0; i < 4; i++) {
        double lb  = 0.025 + (0.075 - 0.025) * (double)i / 3.0;
        double jit = -0.1 + 0.2 * s4[i];
        double li  = lb * (1.0 + jit);
        if (li < 0.0) li = 0.0;
        double di  = 0.01 * sqrt(li / (0.05 + 1e-8));
        lam[i] = (float)li; del[i] = (float)di;
    }

    hipMemsetAsync(ghist, 0, 32*2048*4, stream);
    k_init<<<1, 32, 0, stream>>>(state);

    // 3-pass radix select: bits [31:21], [20:10], [10:0]
    k_hist  <<<dim3(48,32), 256, 0, stream>>>(x, ghist, state, 0u,          21);
    k_select<<<32,          256, 0, stream>>>(ghist, state, scale, 21, 0);
    k_hist  <<<dim3(48,32), 256, 0, stream>>>(x, ghist, state, 0xFFE00000u, 10);
    k_select<<<32,          256, 0, stream>>>(ghist, state, scale, 10, 0);
    k_hist  <<<dim3(48,32), 256, 0, stream>>>(x, ghist, state, 0xFFFFFC00u, 0);
    k_select<<<32,          256, 0, stream>>>(ghist, state, scale, 0, 1);

    k_views<<<dim3(NBAND_,96,4), 256, 0, stream>>>(x, views, scale,
                                               lam[0], lam[1], lam[2], lam[3],
                                               del[0], del[1], del[2], del[3]);
    k_stats<<<dim3(48,32), 256, 0, stream>>>(x, views, pmad, pdev);
    k_final<<<1,           256, 0, stream>>>(pmad, pdev, meanp, out + TOT_);
    k_fuse <<<1536,        256, 0, stream>>>(x, views, meanp, out);
    (void)in_sizes; (void)n_in; (void)out_size; (void)ws_size;
}